// Round 2
// baseline (629.908 us; speedup 1.0000x reference)
//
#include <hip/hip_runtime.h>
#include <hip/hip_bf16.h>

// GCN 2-layer fused pipeline for MI355X.
// Harness delivers integer inputs as int32 — edge_index is const int* [2, E].
// Layer 1 input is [N,1] so layer-1 aggregation is a SCALAR scatter;
// layer 2 output is [N,2] so layer-2 aggregation is a float2 scatter.

__global__ void k_deg(const int* __restrict__ dst, int E,
                      int* __restrict__ deg) {
    int e = blockIdx.x * blockDim.x + threadIdx.x;
    if (e < E) atomicAdd(&deg[dst[e]], 1);
}

// dis[i] = rsqrt(deg_incl_selfloop); p1[i] = x[i]*dis[i]
__global__ void k_dis(const int* __restrict__ deg, const float* __restrict__ x,
                      float* __restrict__ dis, float* __restrict__ p1, int n) {
    int i = blockIdx.x * blockDim.x + threadIdx.x;
    if (i < n) {
        float d = (float)(deg[i] + 1);   // +1 self-loop
        float r = rsqrtf(d);
        dis[i] = r;
        p1[i]  = x[i] * r;
    }
}

// acc1[d] += p1[s]  (scalar layer-1 message)
__global__ void k_scatter1(const int* __restrict__ src,
                           const int* __restrict__ dst,
                           const float* __restrict__ p1,
                           float* __restrict__ acc1, int E) {
    int e = blockIdx.x * blockDim.x + threadIdx.x;
    if (e < E) {
        atomicAdd(&acc1[dst[e]], p1[src[e]]);
    }
}

// Per-node: finish layer1 (norm + self-loop + b1 + relu), apply W2, prescale by dis.
__global__ void k_node(const float* __restrict__ dis, const float* __restrict__ p1,
                       const float* __restrict__ acc1,
                       const float* __restrict__ W1, const float* __restrict__ b1,
                       const float* __restrict__ W2,
                       float* __restrict__ p2, int n) {
    int i = blockIdx.x * blockDim.x + threadIdx.x;
    if (i >= n) return;
    float r   = dis[i];
    float agg = r * (acc1[i] + p1[i]);   // dis*(edge-sum + x*dis self-loop)
    float c0 = 0.f, c1 = 0.f;
#pragma unroll
    for (int k = 0; k < 16; ++k) {
        float v = fmaxf(agg * W1[k] + b1[k], 0.f);  // relu(GCNConv1 out)
        c0 += v * W2[2 * k];
        c1 += v * W2[2 * k + 1];
    }
    p2[2 * i]     = c0 * r;   // prescale by dis[src] for layer-2 message
    p2[2 * i + 1] = c1 * r;
}

// acc2[d][c] += p2[s][c]  (accumulates straight into d_out)
__global__ void k_scatter2(const int* __restrict__ src,
                           const int* __restrict__ dst,
                           const float2* __restrict__ p2,
                           float* __restrict__ acc2, int E) {
    int e = blockIdx.x * blockDim.x + threadIdx.x;
    if (e < E) {
        int s = src[e];
        int d = dst[e];
        float2 v = p2[s];
        atomicAdd(&acc2[2 * d],     v.x);
        atomicAdd(&acc2[2 * d + 1], v.y);
    }
}

// Per-node: finish layer2 (norm + self-loop + b2), exact 2-class log-softmax.
__global__ void k_final(const float* __restrict__ dis, const float* __restrict__ p2,
                        const float* __restrict__ b2, float* __restrict__ out, int n) {
    int i = blockIdx.x * blockDim.x + threadIdx.x;
    if (i >= n) return;
    float r  = dis[i];
    float o0 = r * (out[2 * i]     + p2[2 * i])     + b2[0];
    float o1 = r * (out[2 * i + 1] + p2[2 * i + 1]) + b2[1];
    float m  = fmaxf(o0, o1);
    float ls = m + logf(expf(o0 - m) + expf(o1 - m));
    out[2 * i]     = o0 - ls;
    out[2 * i + 1] = o1 - ls;
}

extern "C" void kernel_launch(void* const* d_in, const int* in_sizes, int n_in,
                              void* d_out, int out_size, void* d_ws, size_t ws_size,
                              hipStream_t stream) {
    const float* x  = (const float*)d_in[0];
    const int*   ei = (const int*)d_in[1];             // int32 [2, E] (harness converts)
    const float* W1 = (const float*)d_in[2];           // [1,16]
    const float* b1 = (const float*)d_in[3];           // [16]
    const float* W2 = (const float*)d_in[4];           // [16,2]
    const float* b2 = (const float*)d_in[5];           // [2]
    float* out = (float*)d_out;                        // [N,2]

    const int n = in_sizes[0];          // 100000
    const int E = in_sizes[1] / 2;      // 3200000

    const int* src = ei;                // edge_index[0]
    const int* dst = ei + E;            // edge_index[1]

    // Workspace layout (all 4-byte elements), total 6N bytes*4 = 2.4 MB:
    char* ws = (char*)d_ws;
    float* dis  = (float*)(ws);                       // N
    float* p1   = (float*)(ws + (size_t)n * 4);       // N
    float* acc1 = (float*)(ws + (size_t)n * 8);       // N
    float* p2   = (float*)(ws + (size_t)n * 12);      // 2N (8B-aligned for even n)
    int*   deg  = (int*)  (ws + (size_t)n * 20);      // N

    hipMemsetAsync(deg,  0, (size_t)n * sizeof(int),       stream);
    hipMemsetAsync(acc1, 0, (size_t)n * sizeof(float),     stream);
    hipMemsetAsync(out,  0, (size_t)n * 2 * sizeof(float), stream);

    const int B = 256;
    const int gridE = (E + B - 1) / B;
    const int gridN = (n + B - 1) / B;

    k_deg     <<<gridE, B, 0, stream>>>(dst, E, deg);
    k_dis     <<<gridN, B, 0, stream>>>(deg, x, dis, p1, n);
    k_scatter1<<<gridE, B, 0, stream>>>(src, dst, p1, acc1, E);
    k_node    <<<gridN, B, 0, stream>>>(dis, p1, acc1, W1, b1, W2, p2, n);
    k_scatter2<<<gridE, B, 0, stream>>>(src, dst, (const float2*)p2, out, E);
    k_final   <<<gridN, B, 0, stream>>>(dis, p2, b2, out, n);
}

// Round 3
// 197.603 us; speedup vs baseline: 3.1877x; 3.1877x over previous
//
#include <hip/hip_runtime.h>
#include <hip/hip_bf16.h>

// GCN 2-layer, atomic-free pipeline for MI355X.
// Key fact from round-2 counters: device-scope atomics write through to HBM
// (32 B per atomic, ~20 G/s) -> 630 us was atomic-bound. Instead: bucket the
// edges by dst (256 nodes/bucket) once, then every aggregation is a per-block
// LDS scatter-add (LDS atomics only, no global atomics, no global memsets).

#define BS        256   // block size
#define NPB       256   // nodes per bucket (dst >> 8)
#define NBSHIFT   8
#define NB_PART   128   // partition blocks

// Per-block histogram of dst buckets.
__global__ void k_hist(const int* __restrict__ dst, int E, int epb, int nbuck,
                       int* __restrict__ hist) {
    __shared__ int h[512];
    for (int i = threadIdx.x; i < nbuck; i += BS) h[i] = 0;
    __syncthreads();
    int b  = blockIdx.x;
    int lo = b * epb, hi = min(E, lo + epb);
    for (int e = lo + threadIdx.x; e < hi; e += BS)
        atomicAdd(&h[dst[e] >> NBSHIFT], 1);
    __syncthreads();
    for (int i = threadIdx.x; i < nbuck; i += BS)
        hist[b * nbuck + i] = h[i];
}

// Single block: column sums -> bucket bases (exclusive scan) -> rewrite
// hist[b][k] in place as the absolute write base for (block b, bucket k).
__global__ void k_scan(int* __restrict__ hist, int nb, int nbuck,
                       int* __restrict__ bucket_base, int E) {
    __shared__ int s[512];
    int k = threadIdx.x;
    int sum = 0;
    if (k < nbuck)
        for (int b = 0; b < nb; ++b) sum += hist[b * nbuck + k];
    s[k] = (k < nbuck) ? sum : 0;
    __syncthreads();
    if (threadIdx.x == 0) {                 // serial exclusive scan, 391 elems
        int run = 0;
        for (int i = 0; i < nbuck; ++i) { int t = s[i]; s[i] = run; run += t; }
    }
    __syncthreads();
    if (k < nbuck) {
        bucket_base[k] = s[k];
        int run = s[k];
        for (int b = 0; b < nb; ++b) {
            int t = hist[b * nbuck + k];
            hist[b * nbuck + k] = run;
            run += t;
        }
    }
    if (k == 0) bucket_base[nbuck] = E;
}

// Scatter packed edge records into bucket-sorted order.
// record = src (bits 0..19) | (dst & 255) << 20
__global__ void k_part(const int* __restrict__ src, const int* __restrict__ dst,
                       int E, int epb, int nbuck,
                       const int* __restrict__ hist,
                       unsigned int* __restrict__ packed) {
    __shared__ int cur[512];
    int b = blockIdx.x;
    for (int i = threadIdx.x; i < nbuck; i += BS) cur[i] = hist[b * nbuck + i];
    __syncthreads();
    int lo = b * epb, hi = min(E, lo + epb);
    for (int e = lo + threadIdx.x; e < hi; e += BS) {
        int d = dst[e];
        int s = src[e];
        int pos = atomicAdd(&cur[d >> NBSHIFT], 1);
        packed[pos] = (unsigned)s | ((unsigned)(d & (NPB - 1)) << 20);
    }
}

// Per-bucket in-degree -> dis = rsqrt(deg+1), p1 = x * dis.
__global__ void k_degdis(const unsigned int* __restrict__ packed,
                         const int* __restrict__ bucket_base,
                         const float* __restrict__ x,
                         float* __restrict__ dis, float* __restrict__ p1, int n) {
    __shared__ int cnt[NPB];
    cnt[threadIdx.x] = 0;
    __syncthreads();
    int k  = blockIdx.x;
    int lo = bucket_base[k], hi = bucket_base[k + 1];
    for (int e = lo + threadIdx.x; e < hi; e += BS)
        atomicAdd(&cnt[packed[e] >> 20], 1);
    __syncthreads();
    int d = (k << NBSHIFT) + threadIdx.x;
    if (d < n) {
        float r = rsqrtf((float)(cnt[threadIdx.x] + 1));
        dis[d] = r;
        p1[d]  = x[d] * r;
    }
}

// Layer-1 aggregation + fused node MLP (W1,b1,relu,W2) + dis prescale -> p2.
__global__ void k_agg1(const unsigned int* __restrict__ packed,
                       const int* __restrict__ bucket_base,
                       const float* __restrict__ dis, const float* __restrict__ p1,
                       const float* __restrict__ W1, const float* __restrict__ b1,
                       const float* __restrict__ W2,
                       float2* __restrict__ p2, int n) {
    __shared__ float acc[NPB];
    acc[threadIdx.x] = 0.f;
    __syncthreads();
    int k  = blockIdx.x;
    int lo = bucket_base[k], hi = bucket_base[k + 1];
    for (int e = lo + threadIdx.x; e < hi; e += BS) {
        unsigned u = packed[e];
        atomicAdd(&acc[u >> 20], p1[u & 0xFFFFFu]);
    }
    __syncthreads();
    int d = (k << NBSHIFT) + threadIdx.x;
    if (d < n) {
        float r   = dis[d];
        float agg = r * (acc[threadIdx.x] + p1[d]);   // includes self-loop
        float c0 = 0.f, c1 = 0.f;
#pragma unroll
        for (int t = 0; t < 16; ++t) {
            float v = fmaxf(fmaf(agg, W1[t], b1[t]), 0.f);
            c0 = fmaf(v, W2[2 * t],     c0);
            c1 = fmaf(v, W2[2 * t + 1], c1);
        }
        p2[d] = make_float2(c0 * r, c1 * r);          // prescaled by dis[src]
    }
}

// Layer-2 aggregation + self-loop + b2 + exact 2-class log-softmax -> out.
__global__ void k_agg2(const unsigned int* __restrict__ packed,
                       const int* __restrict__ bucket_base,
                       const float* __restrict__ dis, const float2* __restrict__ p2,
                       const float* __restrict__ b2,
                       float2* __restrict__ out, int n) {
    __shared__ float a0[NPB], a1[NPB];
    a0[threadIdx.x] = 0.f;
    a1[threadIdx.x] = 0.f;
    __syncthreads();
    int k  = blockIdx.x;
    int lo = bucket_base[k], hi = bucket_base[k + 1];
    for (int e = lo + threadIdx.x; e < hi; e += BS) {
        unsigned u = packed[e];
        float2 v = p2[u & 0xFFFFFu];
        int j = u >> 20;
        atomicAdd(&a0[j], v.x);
        atomicAdd(&a1[j], v.y);
    }
    __syncthreads();
    int d = (k << NBSHIFT) + threadIdx.x;
    if (d < n) {
        float r = dis[d];
        float2 self = p2[d];
        float o0 = r * (a0[threadIdx.x] + self.x) + b2[0];
        float o1 = r * (a1[threadIdx.x] + self.y) + b2[1];
        float m  = fmaxf(o0, o1);
        float ls = m + logf(expf(o0 - m) + expf(o1 - m));
        out[d] = make_float2(o0 - ls, o1 - ls);
    }
}

extern "C" void kernel_launch(void* const* d_in, const int* in_sizes, int n_in,
                              void* d_out, int out_size, void* d_ws, size_t ws_size,
                              hipStream_t stream) {
    const float* x  = (const float*)d_in[0];
    const int*   ei = (const int*)d_in[1];     // int32 [2, E]
    const float* W1 = (const float*)d_in[2];
    const float* b1 = (const float*)d_in[3];
    const float* W2 = (const float*)d_in[4];
    const float* b2 = (const float*)d_in[5];

    const int n = in_sizes[0];                 // 100000
    const int E = in_sizes[1] / 2;             // 3200000
    const int* src = ei;
    const int* dst = ei + E;

    const int nbuck = (n + NPB - 1) >> NBSHIFT;        // 391
    const int epb   = (E + NB_PART - 1) / NB_PART;

    // Workspace layout (8B-aligned chunks).
    char* ws = (char*)d_ws;
    size_t off = 0;
    auto take = [&](size_t bytes) { char* p = ws + off; off += (bytes + 7) & ~(size_t)7; return p; };
    int*          hist        = (int*)take((size_t)NB_PART * nbuck * 4);
    int*          bucket_base = (int*)take((size_t)(nbuck + 1) * 4);
    unsigned int* packed      = (unsigned int*)take((size_t)E * 4);
    float*        dis         = (float*)take((size_t)n * 4);
    float*        p1          = (float*)take((size_t)n * 4);
    float2*       p2          = (float2*)take((size_t)n * 8);

    k_hist  <<<NB_PART, BS, 0, stream>>>(dst, E, epb, nbuck, hist);
    k_scan  <<<1, 512, 0, stream>>>(hist, NB_PART, nbuck, bucket_base, E);
    k_part  <<<NB_PART, BS, 0, stream>>>(src, dst, E, epb, nbuck, hist, packed);
    k_degdis<<<nbuck, BS, 0, stream>>>(packed, bucket_base, x, dis, p1, n);
    k_agg1  <<<nbuck, BS, 0, stream>>>(packed, bucket_base, dis, p1, W1, b1, W2, p2, n);
    k_agg2  <<<nbuck, BS, 0, stream>>>(packed, bucket_base, dis, p2, b2, (float2*)d_out, n);
}

// Round 4
// 134.239 us; speedup vs baseline: 4.6924x; 1.4720x over previous
//
#include <hip/hip_runtime.h>
#include <hip/hip_bf16.h>

// GCN 2-layer, atomic-free pipeline for MI355X.
// Round-3 lesson: k_scan (serial single-block) and k_part (128 blocks, 3.5%
// occupancy) were latency-bound at ~53 us each. This version parallelizes the
// scan (per-bucket block scans + one small base scan) and raises block counts
// everywhere (512 partition blocks, 782 buckets of 128 nodes).

#define BS        256   // block size for edge/bucket kernels
#define NPB       128   // nodes per bucket
#define NBSHIFT   7
#define MAXBUCK   800   // LDS arrays sized for nbuck <= 800

// Per-block histogram of dst buckets, written TRANSPOSED: hist[k*nbp + b].
__global__ void k_hist(const int* __restrict__ dst, int E, int epb, int nbuck,
                       int nbp, int* __restrict__ hist) {
    __shared__ int h[MAXBUCK];
    for (int i = threadIdx.x; i < nbuck; i += BS) h[i] = 0;
    __syncthreads();
    int b  = blockIdx.x;
    int lo = b * epb, hi = min(E, lo + epb);
    for (int e = lo + threadIdx.x; e < hi; e += BS)
        atomicAdd(&h[dst[e] >> NBSHIFT], 1);
    __syncthreads();
    for (int i = threadIdx.x; i < nbuck; i += BS)
        hist[(size_t)i * nbp + b] = h[i];
}

// One block per bucket: exclusive scan of the nbp per-block counts (in place)
// + bucket total. blockDim.x == nbp (<= 512).
__global__ void k_colscan(int* __restrict__ hist, int nbp,
                          int* __restrict__ bucket_sum) {
    __shared__ int s[512];
    int k = blockIdx.x, t = threadIdx.x;
    int v = hist[(size_t)k * nbp + t];
    s[t] = v;
    for (int off = 1; off < nbp; off <<= 1) {
        __syncthreads();
        int a = (t >= off) ? s[t - off] : 0;
        __syncthreads();
        s[t] += a;
    }
    hist[(size_t)k * nbp + t] = s[t] - v;      // exclusive within bucket
    if (t == nbp - 1) bucket_sum[k] = s[t];    // bucket total
}

// Single block: exclusive scan of bucket sums -> bucket_base. nbuck <= 1024.
__global__ void k_base(const int* __restrict__ bucket_sum, int nbuck,
                       int* __restrict__ bucket_base, int E) {
    __shared__ int s[1024];
    int t = threadIdx.x;
    int v = (t < nbuck) ? bucket_sum[t] : 0;
    s[t] = v;
    for (int off = 1; off < 1024; off <<= 1) {
        __syncthreads();
        int a = (t >= off) ? s[t - off] : 0;
        __syncthreads();
        s[t] += a;
    }
    if (t < nbuck) bucket_base[t] = s[t] - v;
    if (t == 0) bucket_base[nbuck] = E;
}

// Scatter packed edge records into bucket-sorted order.
// record = src (bits 0..19) | (dst & 127) << 20
__global__ void k_part(const int* __restrict__ src, const int* __restrict__ dst,
                       int E, int epb, int nbuck, int nbp,
                       const int* __restrict__ hist,
                       const int* __restrict__ bucket_base,
                       unsigned int* __restrict__ packed) {
    __shared__ int cur[MAXBUCK];
    int b = blockIdx.x;
    for (int i = threadIdx.x; i < nbuck; i += BS)
        cur[i] = bucket_base[i] + hist[(size_t)i * nbp + b];
    __syncthreads();
    int lo = b * epb, hi = min(E, lo + epb);
    for (int e = lo + threadIdx.x; e < hi; e += BS) {
        int d = dst[e];
        int s = src[e];
        int pos = atomicAdd(&cur[d >> NBSHIFT], 1);
        packed[pos] = (unsigned)s | ((unsigned)(d & (NPB - 1)) << 20);
    }
}

// Per-bucket in-degree -> dis = rsqrt(deg+1), p1 = x * dis.
__global__ void k_degdis(const unsigned int* __restrict__ packed,
                         const int* __restrict__ bucket_base,
                         const float* __restrict__ x,
                         float* __restrict__ dis, float* __restrict__ p1, int n) {
    __shared__ int cnt[NPB];
    if (threadIdx.x < NPB) cnt[threadIdx.x] = 0;
    __syncthreads();
    int k  = blockIdx.x;
    int lo = bucket_base[k], hi = bucket_base[k + 1];
    for (int e = lo + threadIdx.x; e < hi; e += BS)
        atomicAdd(&cnt[packed[e] >> 20], 1);
    __syncthreads();
    int d = (k << NBSHIFT) + threadIdx.x;
    if (threadIdx.x < NPB && d < n) {
        float r = rsqrtf((float)(cnt[threadIdx.x] + 1));
        dis[d] = r;
        p1[d]  = x[d] * r;
    }
}

// Layer-1 aggregation + fused node MLP (W1,b1,relu,W2) + dis prescale -> p2.
__global__ void k_agg1(const unsigned int* __restrict__ packed,
                       const int* __restrict__ bucket_base,
                       const float* __restrict__ dis, const float* __restrict__ p1,
                       const float* __restrict__ W1, const float* __restrict__ b1,
                       const float* __restrict__ W2,
                       float2* __restrict__ p2, int n) {
    __shared__ float acc[NPB];
    if (threadIdx.x < NPB) acc[threadIdx.x] = 0.f;
    __syncthreads();
    int k  = blockIdx.x;
    int lo = bucket_base[k], hi = bucket_base[k + 1];
    for (int e = lo + threadIdx.x; e < hi; e += BS) {
        unsigned u = packed[e];
        atomicAdd(&acc[u >> 20], p1[u & 0xFFFFFu]);
    }
    __syncthreads();
    int d = (k << NBSHIFT) + threadIdx.x;
    if (threadIdx.x < NPB && d < n) {
        float r   = dis[d];
        float agg = r * (acc[threadIdx.x] + p1[d]);   // includes self-loop
        float c0 = 0.f, c1 = 0.f;
#pragma unroll
        for (int t = 0; t < 16; ++t) {
            float v = fmaxf(fmaf(agg, W1[t], b1[t]), 0.f);
            c0 = fmaf(v, W2[2 * t],     c0);
            c1 = fmaf(v, W2[2 * t + 1], c1);
        }
        p2[d] = make_float2(c0 * r, c1 * r);          // prescaled by dis[src]
    }
}

// Layer-2 aggregation + self-loop + b2 + exact 2-class log-softmax -> out.
__global__ void k_agg2(const unsigned int* __restrict__ packed,
                       const int* __restrict__ bucket_base,
                       const float* __restrict__ dis, const float2* __restrict__ p2,
                       const float* __restrict__ b2,
                       float2* __restrict__ out, int n) {
    __shared__ float a0[NPB], a1[NPB];
    if (threadIdx.x < NPB) { a0[threadIdx.x] = 0.f; a1[threadIdx.x] = 0.f; }
    __syncthreads();
    int k  = blockIdx.x;
    int lo = bucket_base[k], hi = bucket_base[k + 1];
    for (int e = lo + threadIdx.x; e < hi; e += BS) {
        unsigned u = packed[e];
        float2 v = p2[u & 0xFFFFFu];
        int j = u >> 20;
        atomicAdd(&a0[j], v.x);
        atomicAdd(&a1[j], v.y);
    }
    __syncthreads();
    int d = (k << NBSHIFT) + threadIdx.x;
    if (threadIdx.x < NPB && d < n) {
        float r = dis[d];
        float2 self = p2[d];
        float o0 = r * (a0[threadIdx.x] + self.x) + b2[0];
        float o1 = r * (a1[threadIdx.x] + self.y) + b2[1];
        float m  = fmaxf(o0, o1);
        float ls = m + logf(expf(o0 - m) + expf(o1 - m));
        out[d] = make_float2(o0 - ls, o1 - ls);
    }
}

extern "C" void kernel_launch(void* const* d_in, const int* in_sizes, int n_in,
                              void* d_out, int out_size, void* d_ws, size_t ws_size,
                              hipStream_t stream) {
    const float* x  = (const float*)d_in[0];
    const int*   ei = (const int*)d_in[1];     // int32 [2, E]
    const float* W1 = (const float*)d_in[2];
    const float* b1 = (const float*)d_in[3];
    const float* W2 = (const float*)d_in[4];
    const float* b2 = (const float*)d_in[5];

    const int n = in_sizes[0];                 // 100000
    const int E = in_sizes[1] / 2;             // 3200000
    const int* src = ei;
    const int* dst = ei + E;

    const int nbuck = (n + NPB - 1) >> NBSHIFT;            // 782

    // Pick partition-block count by workspace capacity.
    auto need = [&](int nbp_) -> size_t {
        return (size_t)nbuck * nbp_ * 4      // hist
             + (size_t)(2 * nbuck + 2) * 4   // bucket_sum + bucket_base (+pad)
             + (size_t)E * 4                 // packed
             + (size_t)n * 16 + 64;          // dis + p1 + p2 + alignment slack
    };
    int nbp = 512;
    while (nbp > 64 && need(nbp) > ws_size) nbp >>= 1;

    const int epb = (E + nbp - 1) / nbp;

    // Workspace layout (8B-aligned chunks).
    char* ws = (char*)d_ws;
    size_t off = 0;
    auto take = [&](size_t bytes) { char* p = ws + off; off += (bytes + 7) & ~(size_t)7; return p; };
    int*          hist        = (int*)take((size_t)nbuck * nbp * 4);
    int*          bucket_sum  = (int*)take((size_t)nbuck * 4);
    int*          bucket_base = (int*)take((size_t)(nbuck + 1) * 4);
    unsigned int* packed      = (unsigned int*)take((size_t)E * 4);
    float*        dis         = (float*)take((size_t)n * 4);
    float*        p1          = (float*)take((size_t)n * 4);
    float2*       p2          = (float2*)take((size_t)n * 8);

    k_hist   <<<nbp, BS, 0, stream>>>(dst, E, epb, nbuck, nbp, hist);
    k_colscan<<<nbuck, nbp, 0, stream>>>(hist, nbp, bucket_sum);
    k_base   <<<1, 1024, 0, stream>>>(bucket_sum, nbuck, bucket_base, E);
    k_part   <<<nbp, BS, 0, stream>>>(src, dst, E, epb, nbuck, nbp, hist, bucket_base, packed);
    k_degdis <<<nbuck, BS, 0, stream>>>(packed, bucket_base, x, dis, p1, n);
    k_agg1   <<<nbuck, BS, 0, stream>>>(packed, bucket_base, dis, p1, W1, b1, W2, p2, n);
    k_agg2   <<<nbuck, BS, 0, stream>>>(packed, bucket_base, dis, p2, b2, (float2*)d_out, n);
}

// Round 5
// 114.438 us; speedup vs baseline: 5.5044x; 1.1730x over previous
//
#include <hip/hip_runtime.h>

// GCN 2-layer for MI355X — block-major single-pass bucket sort.
// Round-4 lesson: bucket-major scatter = cross-XCD line ping-pong (79 MB
// writes for 12.8 MB payload). Block-major: each partition block sorts its
// 6250 edges in LDS/registers and flushes one contiguous coalesced segment;
// local bucket offsets go to a small offT table. Kills hist/scan kernels.
//
// packed record: src (bits 0..16) | local_dst (bits 17..24)

#define NPB      256    // nodes per aggregation bucket
#define NBSHIFT  8
#define PBS      512    // k_part block threads
#define EPT_MAX  16     // max edges per thread in k_part (epb <= 8192)
#define NPART    512    // partition blocks (fixed; offs LDS sized for it)
#define ABS      512    // aggregation block threads
#define NLANES   16     // lanes per fragment group in agg kernels

__global__ __launch_bounds__(PBS) void k_part(
    const int* __restrict__ src, const int* __restrict__ dst,
    int E, int epb, int nbuck,
    int* __restrict__ offT, unsigned* __restrict__ packed)
{
    __shared__ int s_scan[PBS];
    __shared__ unsigned stage[PBS * EPT_MAX];
    const int b = blockIdx.x, t = threadIdx.x;
    const int lo = b * epb;
    int blockEdges = min(epb, E - lo); if (blockEdges < 0) blockEdges = 0;

    unsigned rec[EPT_MAX];
    int bkt[EPT_MAX];

    s_scan[t] = 0;
    __syncthreads();

    // Phase 1: load edges into registers + LDS bucket histogram.
#pragma unroll
    for (int it = 0; it < EPT_MAX; ++it) {
        int idx = it * PBS + t;
        bkt[it] = -1;
        rec[it] = 0;
        if (idx < blockEdges) {
            int d = dst[lo + idx];
            int s = src[lo + idx];
            rec[it] = (unsigned)s | ((unsigned)(d & (NPB - 1)) << 17);
            bkt[it] = d >> NBSHIFT;
            atomicAdd(&s_scan[bkt[it]], 1);
        }
    }
    __syncthreads();

    // Phase 2: exclusive scan of per-bucket counts (Hillis-Steele, in place).
    int v = s_scan[t];
    for (int off = 1; off < PBS; off <<= 1) {
        __syncthreads();
        int a = (t >= off) ? s_scan[t - off] : 0;
        __syncthreads();
        s_scan[t] += a;
    }
    __syncthreads();
    int excl = s_scan[t] - v;
    __syncthreads();
    s_scan[t] = excl;                       // exclusive offsets, reused as cursors
    if (t < nbuck) offT[(size_t)b * nbuck + t] = excl;
    __syncthreads();

    // Phase 3: scatter records into LDS (block-local counting sort).
#pragma unroll
    for (int it = 0; it < EPT_MAX; ++it) {
        if (bkt[it] >= 0) {
            int pos = atomicAdd(&s_scan[bkt[it]], 1);
            stage[pos] = rec[it];
        }
    }
    __syncthreads();

    // Phase 4: coalesced flush of the block's contiguous segment.
    for (int i = t; i < blockEdges; i += PBS)
        packed[(size_t)lo + i] = stage[i];
}

// ---- aggregation passes: one block per bucket, 16-lane groups per fragment.

__global__ __launch_bounds__(ABS) void k_degdis(
    const unsigned* __restrict__ packed, const int* __restrict__ offT,
    const float* __restrict__ x, int E, int epb, int nbuck, int n,
    float* __restrict__ dis, float* __restrict__ p1)
{
    __shared__ int offs[NPART], nexts[NPART];
    __shared__ int cnt[NPB];
    const int k = blockIdx.x, t = threadIdx.x;
    for (int b = t; b < NPART; b += ABS) {
        offs[b]  = offT[(size_t)b * nbuck + k];
        nexts[b] = (k + 1 < nbuck) ? offT[(size_t)b * nbuck + k + 1] : 0;
    }
    if (t < NPB) cnt[t] = 0;
    __syncthreads();

    const int g = t / NLANES, lane = t % NLANES, NG = ABS / NLANES;
    for (int b = g; b < NPART; b += NG) {
        int off = offs[b];
        int end = (k + 1 < nbuck) ? nexts[b] : max(0, min(epb, E - b * epb));
        const unsigned* pp = packed + (size_t)b * epb + off;
        for (int i = lane; i < end - off; i += NLANES)
            atomicAdd(&cnt[pp[i] >> 17], 1);
    }
    __syncthreads();
    int d = (k << NBSHIFT) + t;
    if (t < NPB && d < n) {
        float r = rsqrtf((float)(cnt[t] + 1));   // +1 self-loop
        dis[d] = r;
        p1[d]  = x[d] * r;
    }
}

__global__ __launch_bounds__(ABS) void k_agg1(
    const unsigned* __restrict__ packed, const int* __restrict__ offT,
    const float* __restrict__ dis, const float* __restrict__ p1,
    const float* __restrict__ W1, const float* __restrict__ b1,
    const float* __restrict__ W2,
    int E, int epb, int nbuck, int n, float2* __restrict__ p2)
{
    __shared__ int offs[NPART], nexts[NPART];
    __shared__ float acc[NPB];
    const int k = blockIdx.x, t = threadIdx.x;
    for (int b = t; b < NPART; b += ABS) {
        offs[b]  = offT[(size_t)b * nbuck + k];
        nexts[b] = (k + 1 < nbuck) ? offT[(size_t)b * nbuck + k + 1] : 0;
    }
    if (t < NPB) acc[t] = 0.f;
    __syncthreads();

    const int g = t / NLANES, lane = t % NLANES, NG = ABS / NLANES;
    for (int b = g; b < NPART; b += NG) {
        int off = offs[b];
        int end = (k + 1 < nbuck) ? nexts[b] : max(0, min(epb, E - b * epb));
        const unsigned* pp = packed + (size_t)b * epb + off;
        for (int i = lane; i < end - off; i += NLANES) {
            unsigned u = pp[i];
            atomicAdd(&acc[u >> 17], p1[u & 0x1FFFFu]);
        }
    }
    __syncthreads();
    int d = (k << NBSHIFT) + t;
    if (t < NPB && d < n) {
        float r   = dis[d];
        float agg = r * (acc[t] + p1[d]);          // + self-loop
        float c0 = 0.f, c1 = 0.f;
#pragma unroll
        for (int j = 0; j < 16; ++j) {
            float h = fmaxf(fmaf(agg, W1[j], b1[j]), 0.f);
            c0 = fmaf(h, W2[2 * j],     c0);
            c1 = fmaf(h, W2[2 * j + 1], c1);
        }
        p2[d] = make_float2(c0 * r, c1 * r);       // prescaled by dis[src]
    }
}

__global__ __launch_bounds__(ABS) void k_agg2(
    const unsigned* __restrict__ packed, const int* __restrict__ offT,
    const float* __restrict__ dis, const float2* __restrict__ p2,
    const float* __restrict__ b2,
    int E, int epb, int nbuck, int n, float2* __restrict__ out)
{
    __shared__ int offs[NPART], nexts[NPART];
    __shared__ float a0[NPB], a1[NPB];
    const int k = blockIdx.x, t = threadIdx.x;
    for (int b = t; b < NPART; b += ABS) {
        offs[b]  = offT[(size_t)b * nbuck + k];
        nexts[b] = (k + 1 < nbuck) ? offT[(size_t)b * nbuck + k + 1] : 0;
    }
    if (t < NPB) { a0[t] = 0.f; a1[t] = 0.f; }
    __syncthreads();

    const int g = t / NLANES, lane = t % NLANES, NG = ABS / NLANES;
    for (int b = g; b < NPART; b += NG) {
        int off = offs[b];
        int end = (k + 1 < nbuck) ? nexts[b] : max(0, min(epb, E - b * epb));
        const unsigned* pp = packed + (size_t)b * epb + off;
        for (int i = lane; i < end - off; i += NLANES) {
            unsigned u = pp[i];
            float2 vv = p2[u & 0x1FFFFu];
            int j = u >> 17;
            atomicAdd(&a0[j], vv.x);
            atomicAdd(&a1[j], vv.y);
        }
    }
    __syncthreads();
    int d = (k << NBSHIFT) + t;
    if (t < NPB && d < n) {
        float r = dis[d];
        float2 self = p2[d];
        float o0 = r * (a0[t] + self.x) + b2[0];
        float o1 = r * (a1[t] + self.y) + b2[1];
        float m  = fmaxf(o0, o1);
        float ls = m + logf(expf(o0 - m) + expf(o1 - m));
        out[d] = make_float2(o0 - ls, o1 - ls);
    }
}

extern "C" void kernel_launch(void* const* d_in, const int* in_sizes, int n_in,
                              void* d_out, int out_size, void* d_ws, size_t ws_size,
                              hipStream_t stream) {
    const float* x  = (const float*)d_in[0];
    const int*   ei = (const int*)d_in[1];     // int32 [2, E]
    const float* W1 = (const float*)d_in[2];
    const float* b1 = (const float*)d_in[3];
    const float* W2 = (const float*)d_in[4];
    const float* b2 = (const float*)d_in[5];

    const int n = in_sizes[0];                 // 100000
    const int E = in_sizes[1] / 2;             // 3200000
    const int* src = ei;
    const int* dst = ei + E;

    const int nbuck = (n + NPB - 1) >> NBSHIFT;        // 391
    const int epb   = (E + NPART - 1) / NPART;         // 6250 (<= PBS*EPT_MAX)

    // Workspace layout.
    char* ws = (char*)d_ws;
    size_t off = 0;
    auto take = [&](size_t bytes) { char* p = ws + off; off += (bytes + 7) & ~(size_t)7; return p; };
    int*      offT   = (int*)take((size_t)NPART * nbuck * 4);   // 800 KB
    unsigned* packed = (unsigned*)take((size_t)E * 4);          // 12.8 MB
    float*    dis    = (float*)take((size_t)n * 4);
    float*    p1     = (float*)take((size_t)n * 4);
    float2*   p2     = (float2*)take((size_t)n * 8);

    k_part  <<<NPART, PBS, 0, stream>>>(src, dst, E, epb, nbuck, offT, packed);
    k_degdis<<<nbuck, ABS, 0, stream>>>(packed, offT, x, E, epb, nbuck, n, dis, p1);
    k_agg1  <<<nbuck, ABS, 0, stream>>>(packed, offT, dis, p1, W1, b1, W2, E, epb, nbuck, n, p2);
    k_agg2  <<<nbuck, ABS, 0, stream>>>(packed, offT, dis, p2, b2, E, epb, nbuck, n, (float2*)d_out);
}

// Round 6
// 100.053 us; speedup vs baseline: 6.2957x; 1.1438x over previous
//
#include <hip/hip_runtime.h>

// GCN 2-layer for MI355X — block-major bucket sort + split aggregation.
// Round-5 lesson: agg kernels were latency-bound (391 blocks = 1.5/CU, 24%
// occupancy, 6% HBM) with 2x packed read amplification (adjacent 64B
// fragments fetched by different XCDs). Fix: S-way split of each bucket's
// work (grid = nbuck*S = 3128 blocks) writing partial accumulators (no
// atomics), node epilogues reduce the partials; XCD-chunked swizzle keeps
// adjacent fragments on the same XCD's L2.
//
// packed record: src (bits 0..16) | local_dst (bits 17..24)

#define NPB      256    // nodes per aggregation bucket
#define NBSHIFT  8
#define PBS      512    // k_part block threads
#define EPT      7      // edges per thread in k_part (epb <= 3584)
#define NPART    1024   // partition blocks
#define ABS      512    // aggregation block threads
#define NLANES   8      // lanes per fragment group (avg fragment ~8 edges)

__device__ __forceinline__ int xcd_swizzle(int wg, int grid) {
    // bijective 8-XCD chunking: each XCD gets a contiguous logical range
    int q = grid >> 3, r = grid & 7;
    int x = wg & 7, i = wg >> 3;
    return (x < r) ? x * (q + 1) + i : r * (q + 1) + (x - r) * q + i;
}

__global__ __launch_bounds__(PBS) void k_part(
    const int* __restrict__ src, const int* __restrict__ dst,
    int E, int epb, int nbuck,
    int* __restrict__ offT, unsigned* __restrict__ packed)
{
    __shared__ int s_scan[PBS];
    __shared__ unsigned stage[PBS * EPT];
    const int b = blockIdx.x, t = threadIdx.x;
    const int lo = b * epb;
    int blockEdges = min(epb, E - lo); if (blockEdges < 0) blockEdges = 0;

    unsigned rec[EPT];
    int bkt[EPT];

    s_scan[t] = 0;
    __syncthreads();

    // Phase 1: load edges into registers + LDS bucket histogram.
#pragma unroll
    for (int it = 0; it < EPT; ++it) {
        int idx = it * PBS + t;
        bkt[it] = -1;
        rec[it] = 0;
        if (idx < blockEdges) {
            int d = dst[lo + idx];
            int s = src[lo + idx];
            rec[it] = (unsigned)s | ((unsigned)(d & (NPB - 1)) << 17);
            bkt[it] = d >> NBSHIFT;
            atomicAdd(&s_scan[bkt[it]], 1);
        }
    }
    __syncthreads();

    // Phase 2: exclusive scan (Hillis-Steele) of per-bucket counts.
    int v = s_scan[t];
    for (int off = 1; off < PBS; off <<= 1) {
        __syncthreads();
        int a = (t >= off) ? s_scan[t - off] : 0;
        __syncthreads();
        s_scan[t] += a;
    }
    __syncthreads();
    int excl = s_scan[t] - v;
    __syncthreads();
    s_scan[t] = excl;                       // reuse as scatter cursors
    if (t < nbuck) offT[(size_t)b * nbuck + t] = excl;
    __syncthreads();

    // Phase 3: block-local counting sort into LDS.
#pragma unroll
    for (int it = 0; it < EPT; ++it) {
        if (bkt[it] >= 0) {
            int pos = atomicAdd(&s_scan[bkt[it]], 1);
            stage[pos] = rec[it];
        }
    }
    __syncthreads();

    // Phase 4: coalesced flush of the block's contiguous segment.
    for (int i = t; i < blockEdges; i += PBS)
        packed[(size_t)lo + i] = stage[i];
}

// ---- split aggregation: one block per (bucket k, split s); partial outputs.

__global__ __launch_bounds__(ABS) void k_deg_split(
    const unsigned* __restrict__ packed, const int* __restrict__ offT,
    int E, int epb, int nbuck, int S, int split_nb,
    int* __restrict__ pc)
{
    __shared__ int offs[1024], ends[1024];
    __shared__ int cnt[NPB];
    const int L = xcd_swizzle(blockIdx.x, gridDim.x);
    const int k = L % nbuck, s = L / nbuck;
    const int t = threadIdx.x;
    const int bstart = s * split_nb;
    for (int j = t; j < split_nb; j += ABS) {
        int b = bstart + j;
        offs[j] = offT[(size_t)b * nbuck + k];
        ends[j] = (k + 1 < nbuck) ? offT[(size_t)b * nbuck + k + 1]
                                  : max(0, min(epb, E - b * epb));
    }
    if (t < NPB) cnt[t] = 0;
    __syncthreads();

    const int g = t / NLANES, lane = t % NLANES, NG = ABS / NLANES;
    for (int j = g; j < split_nb; j += NG) {
        const unsigned* pp = packed + (size_t)(bstart + j) * epb;
        int end = ends[j];
        for (int i = offs[j] + lane; i < end; i += NLANES)
            atomicAdd(&cnt[pp[i] >> 17], 1);
    }
    __syncthreads();
    if (t < NPB) pc[((size_t)s * nbuck + k) * NPB + t] = cnt[t];
}

__global__ __launch_bounds__(ABS) void k_agg1_split(
    const unsigned* __restrict__ packed, const int* __restrict__ offT,
    const float* __restrict__ p1,
    int E, int epb, int nbuck, int S, int split_nb,
    float* __restrict__ pa1)
{
    __shared__ int offs[1024], ends[1024];
    __shared__ float acc[NPB];
    const int L = xcd_swizzle(blockIdx.x, gridDim.x);
    const int k = L % nbuck, s = L / nbuck;
    const int t = threadIdx.x;
    const int bstart = s * split_nb;
    for (int j = t; j < split_nb; j += ABS) {
        int b = bstart + j;
        offs[j] = offT[(size_t)b * nbuck + k];
        ends[j] = (k + 1 < nbuck) ? offT[(size_t)b * nbuck + k + 1]
                                  : max(0, min(epb, E - b * epb));
    }
    if (t < NPB) acc[t] = 0.f;
    __syncthreads();

    const int g = t / NLANES, lane = t % NLANES, NG = ABS / NLANES;
    for (int j = g; j < split_nb; j += NG) {
        const unsigned* pp = packed + (size_t)(bstart + j) * epb;
        int end = ends[j];
        for (int i = offs[j] + lane; i < end; i += NLANES) {
            unsigned u = pp[i];
            atomicAdd(&acc[u >> 17], p1[u & 0x1FFFFu]);
        }
    }
    __syncthreads();
    if (t < NPB) pa1[((size_t)s * nbuck + k) * NPB + t] = acc[t];
}

__global__ __launch_bounds__(ABS) void k_agg2_split(
    const unsigned* __restrict__ packed, const int* __restrict__ offT,
    const float2* __restrict__ p2,
    int E, int epb, int nbuck, int S, int split_nb,
    float2* __restrict__ pa2)
{
    __shared__ int offs[1024], ends[1024];
    __shared__ float a0[NPB], a1[NPB];
    const int L = xcd_swizzle(blockIdx.x, gridDim.x);
    const int k = L % nbuck, s = L / nbuck;
    const int t = threadIdx.x;
    const int bstart = s * split_nb;
    for (int j = t; j < split_nb; j += ABS) {
        int b = bstart + j;
        offs[j] = offT[(size_t)b * nbuck + k];
        ends[j] = (k + 1 < nbuck) ? offT[(size_t)b * nbuck + k + 1]
                                  : max(0, min(epb, E - b * epb));
    }
    if (t < NPB) { a0[t] = 0.f; a1[t] = 0.f; }
    __syncthreads();

    const int g = t / NLANES, lane = t % NLANES, NG = ABS / NLANES;
    for (int j = g; j < split_nb; j += NG) {
        const unsigned* pp = packed + (size_t)(bstart + j) * epb;
        int end = ends[j];
        for (int i = offs[j] + lane; i < end; i += NLANES) {
            unsigned u = pp[i];
            float2 vv = p2[u & 0x1FFFFu];
            int d = u >> 17;
            atomicAdd(&a0[d], vv.x);
            atomicAdd(&a1[d], vv.y);
        }
    }
    __syncthreads();
    if (t < NPB)
        pa2[((size_t)s * nbuck + k) * NPB + t] = make_float2(a0[t], a1[t]);
}

// ---- node epilogues (reduce S partials, fuse the pointwise math).

__global__ void k_dis(const int* __restrict__ pc, const float* __restrict__ x,
                      int nbuck, int S, int n,
                      float* __restrict__ dis, float* __restrict__ p1) {
    int d = blockIdx.x * blockDim.x + threadIdx.x;
    if (d >= n) return;
    size_t nround = (size_t)nbuck * NPB;
    int c = 0;
    for (int s = 0; s < S; ++s) c += pc[s * nround + d];
    float r = rsqrtf((float)(c + 1));          // +1 self-loop
    dis[d] = r;
    p1[d]  = x[d] * r;
}

__global__ void k_node(const float* __restrict__ pa1,
                       const float* __restrict__ dis, const float* __restrict__ p1,
                       const float* __restrict__ W1, const float* __restrict__ b1,
                       const float* __restrict__ W2,
                       int nbuck, int S, int n, float2* __restrict__ p2) {
    int d = blockIdx.x * blockDim.x + threadIdx.x;
    if (d >= n) return;
    size_t nround = (size_t)nbuck * NPB;
    float a = 0.f;
    for (int s = 0; s < S; ++s) a += pa1[s * nround + d];
    float r   = dis[d];
    float agg = r * (a + p1[d]);               // + self-loop
    float c0 = 0.f, c1 = 0.f;
#pragma unroll
    for (int j = 0; j < 16; ++j) {
        float h = fmaxf(fmaf(agg, W1[j], b1[j]), 0.f);
        c0 = fmaf(h, W2[2 * j],     c0);
        c1 = fmaf(h, W2[2 * j + 1], c1);
    }
    p2[d] = make_float2(c0 * r, c1 * r);       // prescaled by dis[src]
}

__global__ void k_final(const float2* __restrict__ pa2,
                        const float* __restrict__ dis, const float2* __restrict__ p2,
                        const float* __restrict__ b2,
                        int nbuck, int S, int n, float2* __restrict__ out) {
    int d = blockIdx.x * blockDim.x + threadIdx.x;
    if (d >= n) return;
    size_t nround = (size_t)nbuck * NPB;
    float a0 = 0.f, a1 = 0.f;
    for (int s = 0; s < S; ++s) {
        float2 v = pa2[s * nround + d];
        a0 += v.x; a1 += v.y;
    }
    float r = dis[d];
    float2 self = p2[d];
    float o0 = r * (a0 + self.x) + b2[0];
    float o1 = r * (a1 + self.y) + b2[1];
    float m  = fmaxf(o0, o1);
    float ls = m + logf(expf(o0 - m) + expf(o1 - m));
    out[d] = make_float2(o0 - ls, o1 - ls);
}

extern "C" void kernel_launch(void* const* d_in, const int* in_sizes, int n_in,
                              void* d_out, int out_size, void* d_ws, size_t ws_size,
                              hipStream_t stream) {
    const float* x  = (const float*)d_in[0];
    const int*   ei = (const int*)d_in[1];     // int32 [2, E]
    const float* W1 = (const float*)d_in[2];
    const float* b1 = (const float*)d_in[3];
    const float* W2 = (const float*)d_in[4];
    const float* b2 = (const float*)d_in[5];

    const int n = in_sizes[0];                 // 100000
    const int E = in_sizes[1] / 2;             // 3200000
    const int* src = ei;
    const int* dst = ei + E;

    const int nbuck = (n + NPB - 1) >> NBSHIFT;        // 391
    const int epb   = (E + NPART - 1) / NPART;         // 3125 (<= PBS*EPT)
    const size_t nround = (size_t)nbuck * NPB;

    // Choose split factor by workspace capacity.
    auto need = [&](int S_) -> size_t {
        return (size_t)NPART * nbuck * 4           // offT
             + (size_t)E * 4                       // packed
             + (size_t)S_ * nround * 16            // pc + pa1 + pa2
             + (size_t)n * 16 + 256;               // dis + p1 + p2 + slack
    };
    int S = 8;
    while (S > 1 && need(S) > ws_size) S >>= 1;
    const int split_nb = NPART / S;

    // Workspace layout.
    char* ws = (char*)d_ws;
    size_t off = 0;
    auto take = [&](size_t bytes) { char* p = ws + off; off += (bytes + 7) & ~(size_t)7; return p; };
    int*      offT   = (int*)take((size_t)NPART * nbuck * 4);
    unsigned* packed = (unsigned*)take((size_t)E * 4);
    int*      pc     = (int*)take((size_t)S * nround * 4);
    float*    pa1    = (float*)take((size_t)S * nround * 4);
    float2*   pa2    = (float2*)take((size_t)S * nround * 8);
    float*    dis    = (float*)take((size_t)n * 4);
    float*    p1     = (float*)take((size_t)n * 4);
    float2*   p2     = (float2*)take((size_t)n * 8);

    const int gridAgg = nbuck * S;
    const int gridN   = (n + 255) / 256;

    k_part      <<<NPART, PBS, 0, stream>>>(src, dst, E, epb, nbuck, offT, packed);
    k_deg_split <<<gridAgg, ABS, 0, stream>>>(packed, offT, E, epb, nbuck, S, split_nb, pc);
    k_dis       <<<gridN, 256, 0, stream>>>(pc, x, nbuck, S, n, dis, p1);
    k_agg1_split<<<gridAgg, ABS, 0, stream>>>(packed, offT, p1, E, epb, nbuck, S, split_nb, pa1);
    k_node      <<<gridN, 256, 0, stream>>>(pa1, dis, p1, W1, b1, W2, nbuck, S, n, p2);
    k_agg2_split<<<gridAgg, ABS, 0, stream>>>(packed, offT, p2, E, epb, nbuck, S, split_nb, pa2);
    k_final     <<<gridN, 256, 0, stream>>>(pa2, dis, p2, b2, nbuck, S, n, (float2*)d_out);
}